// Round 2
// baseline (289.322 us; speedup 1.0000x reference)
//
#include <hip/hip_runtime.h>
#include <cstdint>

constexpr int SEQ  = 2048;
constexpr int DIN  = 1024;
constexpr int DQK  = 128;
constexpr int NB   = 8;
constexpr int MTOT = NB * SEQ;   // 16384
constexpr float INV_SCALE = 0.08838834764831845f;  // 1/sqrt(128)

typedef __attribute__((ext_vector_type(8))) short  short8;
typedef __attribute__((ext_vector_type(4))) float  floatx4;
typedef __attribute__((ext_vector_type(4))) int    intx4;

struct GM { unsigned long long w[32]; };   // 2048-bit global-token mask

// ---------------------------------------------------------------------------
// Host-side reproduction of np.random.default_rng(0).choice(2048, 32, False).
// (verified correct since Round 1)
// ---------------------------------------------------------------------------
static void compute_gtok(unsigned long long bits[32]) {
  typedef unsigned __int128 u128;
  uint32_t pool[4];
  uint32_t hc = 0x43b0d7e5u;
  auto hashmix = [&hc](uint32_t v) -> uint32_t {
    v ^= hc; hc *= 0x931e8875u; v *= hc; v ^= v >> 16; return v;
  };
  auto mixf = [](uint32_t x, uint32_t y) -> uint32_t {
    uint32_t r = x * 0xca01f9ddu - y * 0x4973f715u;
    r ^= r >> 16; return r;
  };
  pool[0] = hashmix(0u);
  for (int i = 1; i < 4; ++i) pool[i] = hashmix(0u);
  for (int s = 0; s < 4; ++s)
    for (int d = 0; d < 4; ++d)
      if (s != d) pool[d] = mixf(pool[d], hashmix(pool[s]));
  uint32_t hb = 0x8b51f9ddu;
  uint32_t st[8];
  for (int i = 0; i < 8; ++i) {
    uint32_t dv = pool[i & 3];
    dv ^= hb; hb *= 0x58f38dedu; dv *= hb; dv ^= dv >> 16;
    st[i] = dv;
  }
  uint64_t sv[4];
  for (int i = 0; i < 4; ++i)
    sv[i] = (uint64_t)st[2 * i] | ((uint64_t)st[2 * i + 1] << 32);
  const u128 MUL = ((u128)2549297995355413924ULL << 64) | (u128)4865540595714422341ULL;
  u128 initstate = ((u128)sv[0] << 64) | sv[1];
  u128 initseq   = ((u128)sv[2] << 64) | sv[3];
  u128 state = 0;
  u128 inc = (initseq << 1) | 1;
  state = state * MUL + inc;
  state += initstate;
  state = state * MUL + inc;
  bool has32 = false; uint32_t cache32 = 0;
  auto next64 = [&]() -> uint64_t {
    state = state * MUL + inc;
    uint64_t hi = (uint64_t)(state >> 64);
    uint64_t lo = (uint64_t)state;
    unsigned rot = (unsigned)(state >> 122);
    uint64_t x = hi ^ lo;
    return (x >> rot) | (x << ((64u - rot) & 63u));
  };
  auto next32 = [&]() -> uint32_t {
    if (has32) { has32 = false; return cache32; }
    uint64_t n = next64();
    has32 = true; cache32 = (uint32_t)(n >> 32);
    return (uint32_t)n;
  };
  bool in_set[SEQ];
  for (int i = 0; i < SEQ; ++i) in_set[i] = false;
  for (uint32_t j = 2016; j < 2048; ++j) {
    uint32_t rng_excl = j + 1;
    uint64_t m = (uint64_t)next32() * rng_excl;
    uint32_t leftover = (uint32_t)m;
    if (leftover < rng_excl) {
      uint32_t threshold = (0xFFFFFFFFu - j) % rng_excl;
      while (leftover < threshold) {
        m = (uint64_t)next32() * rng_excl;
        leftover = (uint32_t)m;
      }
    }
    uint32_t val = (uint32_t)(m >> 32);
    if (in_set[val]) in_set[j] = true;
    else in_set[val] = true;
  }
  for (int i = 0; i < 32; ++i) bits[i] = 0ULL;
  for (int t = 0; t < SEQ; ++t)
    if (in_set[t]) bits[t >> 6] |= (1ULL << (t & 63));
}

// ---------------------------------------------------------------------------
// helpers
// ---------------------------------------------------------------------------
__device__ __forceinline__ void ldsld16(const void* g, void* l) {
  __builtin_amdgcn_global_load_lds(
      (const __attribute__((address_space(1))) unsigned int*)g,
      (__attribute__((address_space(3))) unsigned int*)l, 16, 0, 0);
}
__device__ __forceinline__ bool gbit(const GM& g, int j) {
  return (g.w[j >> 6] >> (j & 63)) & 1ULL;
}
// trunc-hi split: hi = RTZ bf16, lo = RTZ bf16 of residual (covered by 3-term)
__device__ __forceinline__ void split4(float4 x, unsigned hw[2], unsigned lw[2]) {
  unsigned u0 = __float_as_uint(x.x), u1 = __float_as_uint(x.y);
  unsigned u2 = __float_as_uint(x.z), u3 = __float_as_uint(x.w);
  hw[0] = __builtin_amdgcn_perm(u1, u0, 0x07060302u);
  hw[1] = __builtin_amdgcn_perm(u3, u2, 0x07060302u);
  unsigned r0 = __float_as_uint(x.x - __uint_as_float(u0 & 0xFFFF0000u));
  unsigned r1 = __float_as_uint(x.y - __uint_as_float(u1 & 0xFFFF0000u));
  unsigned r2 = __float_as_uint(x.z - __uint_as_float(u2 & 0xFFFF0000u));
  unsigned r3 = __float_as_uint(x.w - __uint_as_float(u3 & 0xFFFF0000u));
  lw[0] = __builtin_amdgcn_perm(r1, r0, 0x07060302u);
  lw[1] = __builtin_amdgcn_perm(r3, r2, 0x07060302u);
}
__device__ __forceinline__ void split1(float v, unsigned short& h, unsigned short& l) {
  unsigned u = __float_as_uint(v);
  h = (unsigned short)(u >> 16);
  float rr = v - __uint_as_float(u & 0xFFFF0000u);
  l = (unsigned short)(__float_as_uint(rr) >> 16);
}
__device__ __forceinline__ unsigned short bfr_rne(float v) {   // fp32->bf16 RNE
  unsigned u = __float_as_uint(v);
  return (unsigned short)((u + 0x7FFFu + ((u >> 16) & 1u)) >> 16);
}

// ---------------------------------------------------------------------------
// Kernel 0: convert W (3 x [128][1024] fp32) to hi/lo bf16 planes (flat).
// ---------------------------------------------------------------------------
__global__ __launch_bounds__(256) void wconv_kernel(
    const float* __restrict__ Wq, const float* __restrict__ Wk, const float* __restrict__ Wv,
    unsigned short* __restrict__ Whi, unsigned short* __restrict__ Wlo) {
  const float* W = blockIdx.y == 0 ? Wq : blockIdx.y == 1 ? Wk : Wv;
  size_t base = (size_t)blockIdx.y * DQK * DIN;
  int e = (blockIdx.x * 256 + threadIdx.x) * 4;
  float4 x = *(const float4*)&W[e];
  unsigned hw[2], lw[2];
  split4(x, hw, lw);
  *(uint2*)&Whi[base + e] = make_uint2(hw[0], hw[1]);
  *(uint2*)&Wlo[base + e] = make_uint2(lw[0], lw[1]);
}

// ---------------------------------------------------------------------------
// Kernel 1: projections via bf16 MFMA with hi/lo split (fp32-accurate).
// 64x128 block tile (grid 256x3 = 768 blocks = exactly 3/CU), 4 waves of
// 32x64 (2x4 of 16x16x32), K-chunk 64, 48KB LDS -> 3 blocks/CU resident.
// Round-1 change (T14): X and W are REGISTER-prefetched one K-chunk ahead;
// the stage->MFMA barrier is a raw lgkmcnt(0)+s_barrier so the prefetch
// loads stay in flight under the MFMA phase (no vmcnt(0) drain there).
// which 0/1 -> Q/K bf16 [s][d]; which 2 -> Vt single RNE bf16 [b][d][s].
// ---------------------------------------------------------------------------
__global__ __launch_bounds__(256, 3) void proj_kernel(
    const float* __restrict__ xq, const float* __restrict__ xk, const float* __restrict__ xv,
    const unsigned short* __restrict__ Whi, const unsigned short* __restrict__ Wlo,
    const float* __restrict__ bq, const float* __restrict__ bk, const float* __restrict__ bv,
    unsigned short* __restrict__ Qb, unsigned short* __restrict__ Kb,
    unsigned short* __restrict__ Vth) {
  const int which = blockIdx.y;
  const float* X    = which == 0 ? xq : which == 1 ? xk : xv;
  const float* bias = which == 0 ? bq : which == 1 ? bk : bv;
  const int m0 = blockIdx.x * 64;

  __shared__ unsigned short Xh[64 * 64];    // 8KB
  __shared__ unsigned short Xl[64 * 64];    // 8KB
  __shared__ unsigned short Wh[128 * 64];   // 16KB (reused as VH in V epilogue)
  __shared__ unsigned short Wl[128 * 64];   // 16KB

  const int tid = threadIdx.x;
  const int w = tid >> 6, lane = tid & 63, l15 = lane & 15, quad = lane >> 4;
  const int mh = (w >> 1) * 32, nh = (w & 1) * 64;

  floatx4 acc[2][4] = {};
  float biasv[4];
#pragma unroll
  for (int j = 0; j < 4; ++j) biasv[j] = bias[nh + j * 16 + l15];

  const unsigned short* WhiP = Whi + (size_t)which * DQK * DIN;
  const unsigned short* WloP = Wlo + (size_t)which * DQK * DIN;

  // ---- per-thread loop-invariant staging addresses ----
  // X: 4 chunks of float4
  const float* xsrc[4];
  int xoff[4];
#pragma unroll
  for (int i = 0; i < 4; ++i) {
    int f = tid + i * 256;
    int r = f >> 4, c4 = f & 15;
    xsrc[i] = &X[(size_t)(m0 + r) * DIN + c4 * 4];     // + kb at load time
    xoff[i] = r * 64 + (((c4 >> 1) ^ (r & 7)) * 8) + (c4 & 1) * 4;
  }
  // W: 8 chunks of 16B (reg-staged; LDS dest matches old gload_lds layout:
  // chunk base c*1024 bytes + lane*16 bytes)
  const unsigned short* wsrc[8];
  unsigned short* wdst[8];
#pragma unroll
  for (int i = 0; i < 8; ++i) {
    int c = w * 8 + i;                 // 0..31: plane = c>>4, chunk cc = c&15
    int plane = c >> 4, cc = c & 15;
    int F = cc * 1024 + lane * 16;     // byte in 16KB plane tile
    int n = F >> 7, gs = (F >> 4) & 7, gl = gs ^ (n & 7);
    wsrc[i] = (plane ? WloP : WhiP) + (size_t)n * DIN + gl * 8;   // + kb at load time
    wdst[i] = (unsigned short*)((char*)(plane ? Wl : Wh) + cc * 1024) + lane * 8;
  }

  // ---- prologue: issue prefetch for kb = 0 ----
  float4 xr[4];
  intx4  wr[8];
#pragma unroll
  for (int i = 0; i < 4; ++i) xr[i] = *(const float4*)xsrc[i];
#pragma unroll
  for (int i = 0; i < 8; ++i) wr[i] = *(const intx4*)wsrc[i];

  for (int kb = 0; kb < DIN; kb += 64) {
    __syncthreads();   // prev MFMA reads done; also drains this chunk's loads
    // --- write staged X (convert) and W to LDS ---
#pragma unroll
    for (int i = 0; i < 4; ++i) {
      unsigned hw[2], lw[2];
      split4(xr[i], hw, lw);
      *(uint2*)&Xh[xoff[i]] = make_uint2(hw[0], hw[1]);
      *(uint2*)&Xl[xoff[i]] = make_uint2(lw[0], lw[1]);
    }
#pragma unroll
    for (int i = 0; i < 8; ++i) *(intx4*)wdst[i] = wr[i];
    // --- issue prefetch for next chunk (stays in flight during MFMA) ---
    if (kb + 64 < DIN) {
#pragma unroll
      for (int i = 0; i < 4; ++i) xr[i] = *(const float4*)(xsrc[i] + kb + 64);
#pragma unroll
      for (int i = 0; i < 8; ++i) wr[i] = *(const intx4*)(wsrc[i] + kb + 64);
    }
    // raw barrier: LDS writes visible, but NO vmcnt drain (keep prefetch async)
    asm volatile("s_waitcnt lgkmcnt(0)" ::: "memory");
    __builtin_amdgcn_s_barrier();
    // --- MFMA: 2 k-steps of 32, hi/lo 3-term product ---
#pragma unroll
    for (int ks = 0; ks < 2; ++ks) {
      short8 Ah[2], Al[2], Bh[4], Bl[4];
#pragma unroll
      for (int ms = 0; ms < 2; ++ms) {
        int off = (mh + ms * 16 + l15) * 64 + (((ks * 4 + quad) ^ (l15 & 7)) * 8);
        Ah[ms] = *(const short8*)&Xh[off];
        Al[ms] = *(const short8*)&Xl[off];
      }
#pragma unroll
      for (int ns = 0; ns < 4; ++ns) {
        int off = (nh + ns * 16 + l15) * 64 + (((ks * 4 + quad) ^ (l15 & 7)) * 8);
        Bh[ns] = *(const short8*)&Wh[off];
        Bl[ns] = *(const short8*)&Wl[off];
      }
#pragma unroll
      for (int i = 0; i < 2; ++i)
#pragma unroll
        for (int j = 0; j < 4; ++j) {
          floatx4 c = acc[i][j];
          c = __builtin_amdgcn_mfma_f32_16x16x32_bf16(Ah[i], Bh[j], c, 0, 0, 0);
          c = __builtin_amdgcn_mfma_f32_16x16x32_bf16(Ah[i], Bl[j], c, 0, 0, 0);
          c = __builtin_amdgcn_mfma_f32_16x16x32_bf16(Al[i], Bh[j], c, 0, 0, 0);
          acc[i][j] = c;
        }
    }
  }

  // --- epilogue ---
  if (which < 2) {
    unsigned short* O = which == 0 ? Qb : Kb;
#pragma unroll
    for (int i = 0; i < 2; ++i)
#pragma unroll
      for (int j = 0; j < 4; ++j)
#pragma unroll
        for (int r = 0; r < 4; ++r) {
          int m = mh + i * 16 + quad * 4 + r;
          int n = nh + j * 16 + l15;
          O[(size_t)(m0 + m) * DQK + n] = bfr_rne(acc[i][j][r] + biasv[j]);
        }
  } else {
    // V: add bias, single RNE bf16, transpose to [d][s] via LDS (reuse Wh)
    __syncthreads();
    unsigned short* VH = Wh;   // 128(d) x 64(s) bf16, swizzled
#pragma unroll
    for (int i = 0; i < 2; ++i)
#pragma unroll
      for (int j = 0; j < 4; ++j)
#pragma unroll
        for (int r = 0; r < 4; ++r) {
          int s = mh + i * 16 + quad * 4 + r;
          int d = nh + j * 16 + l15;
          VH[d * 64 + (((s >> 3) ^ (d & 7)) * 8) + (s & 7)] =
              bfr_rne(acc[i][j][r] + biasv[j]);
        }
    __syncthreads();
    int b = m0 >> 11, s0 = m0 & 2047;
#pragma unroll
    for (int i = 0; i < 4; ++i) {
      int cch = i * 256 + tid;          // 1024 16B-chunks
      int d = cch >> 3, gI = cch & 7;
      int loff = d * 64 + ((gI ^ (d & 7)) * 8);
      intx4 vh = *(const intx4*)&VH[loff];
      *(intx4*)&Vth[((size_t)b * DQK + d) * SEQ + s0 + gI * 8] = vh;
    }
  }
}

// ---------------------------------------------------------------------------
// Kernel 2: flash attention, MFMA, 3-way split-KV (kt % 3 classes).
// grid.x = 96 (qt = x/3, s = x%3), grid.y = batch -> 768 blocks = 3/CU
// (50KB LDS, __launch_bounds__(256,3)). V single bf16 plane; P kept hi/lo
// (2-term PV). Writes UNNORMALIZED partial O + (m,l); merge3 combines.
// ---------------------------------------------------------------------------
__global__ __launch_bounds__(256, 3) void attn_kernel(
    const unsigned short* __restrict__ Qb, const unsigned short* __restrict__ Kb,
    const unsigned short* __restrict__ Vth,
    float* __restrict__ Opart, float2* __restrict__ ML, GM g, unsigned int t64) {
  __shared__ unsigned short Ks[64 * 128];   // swizzled, 16KB
  __shared__ unsigned short Vh[128 * 64];   // swizzled, 16KB
  __shared__ unsigned short Ph[4][16 * 72]; // per-wave P hi strips (stride 72)
  __shared__ unsigned short Pl[4][16 * 72]; // per-wave P lo strips

  const int tid = threadIdx.x;
  const int w = tid >> 6, lane = tid & 63, l15 = lane & 15, quad = lane >> 4;
  const int b = blockIdx.y;
  const int qt = blockIdx.x / 3, s3 = blockIdx.x - qt * 3;
  const int qs = qt * 64;

  // Q fragments (A-layout), held in registers for the whole block
  short8 qf[4];
  const unsigned short* Qrow = Qb + ((size_t)(b * SEQ + qs + w * 16 + l15)) * DQK;
#pragma unroll
  for (int j = 0; j < 4; ++j) qf[j] = *(const short8*)&Qrow[j * 32 + quad * 8];

  int rowi[4]; bool growb[4];
#pragma unroll
  for (int r = 0; r < 4; ++r) {
    rowi[r] = qs + w * 16 + quad * 4 + r;
    growb[r] = gbit(g, rowi[r]);
  }

  floatx4 o[8] = {};
  float m_r[4] = {-1e30f, -1e30f, -1e30f, -1e30f};
  float l_r[4] = {0.f, 0.f, 0.f, 0.f};

  const bool qhasg = (t64 >> qt) & 1;
  const unsigned short* KbB = Kb  + (size_t)b * SEQ * DQK;
  const unsigned short* VhB = Vth + (size_t)b * DQK * SEQ;

  for (int kt = s3; kt < 32; kt += 3) {    // 3-way split-KV
    const int ks0 = kt * 64;
    if (!((ks0 <= qs + 63) || ((t64 >> kt) & 1) || qhasg)) continue;   // block-uniform

    __syncthreads();   // prior tile's LDS reads complete
    // --- stage K / Vt (32 x 1KB chunks, swizzled gather) ---
#pragma unroll
    for (int i = 0; i < 8; ++i) {
      int c = w * 8 + i;
      if (c < 16) {
        int F = c * 1024 + lane * 16;
        int r = F >> 8, gs = (F >> 4) & 15, gl = gs ^ (r & 15);
        ldsld16(KbB + (size_t)(ks0 + r) * DQK + gl * 8, (char*)Ks + c * 1024);
      } else {
        int cc = c - 16;
        int F = cc * 1024 + lane * 16;
        int d = F >> 7, gs = (F >> 4) & 7, gl = gs ^ (d & 7);
        ldsld16(VhB + (size_t)d * SEQ + ks0 + gl * 8, (char*)Vh + cc * 1024);
      }
    }
    __syncthreads();   // staging visible

    // --- QK^T: S strip [16 q x 64 k] per wave ---
    floatx4 S[4];
#pragma unroll
    for (int c4 = 0; c4 < 4; ++c4) {
      floatx4 s = {0.f, 0.f, 0.f, 0.f};
#pragma unroll
      for (int j = 0; j < 4; ++j) {
        short8 kf = *(const short8*)&Ks[(c4 * 16 + l15) * 128 + (((j * 4 + quad) ^ l15) * 8)];
        s = __builtin_amdgcn_mfma_f32_16x16x32_bf16(qf[j], kf, s, 0, 0, 0);
      }
      S[c4] = s;
    }

    // --- mask + scale + online softmax ---
    float z[4][4];
    float mx[4] = {-1e30f, -1e30f, -1e30f, -1e30f};
#pragma unroll
    for (int c4 = 0; c4 < 4; ++c4) {
      int col = ks0 + c4 * 16 + l15;
      bool cg = gbit(g, col);
#pragma unroll
      for (int r = 0; r < 4; ++r) {
        bool ok = (col <= rowi[r]) || cg || growb[r];
        float zz = ok ? S[c4][r] * INV_SCALE : -1e30f;
        z[c4][r] = zz;
        mx[r] = fmaxf(mx[r], zz);
      }
    }
#pragma unroll
    for (int d = 1; d < 16; d <<= 1)
#pragma unroll
      for (int r = 0; r < 4; ++r) mx[r] = fmaxf(mx[r], __shfl_xor(mx[r], d));
    float alpha[4], rs[4] = {0.f, 0.f, 0.f, 0.f};
#pragma unroll
    for (int r = 0; r < 4; ++r) {
      float mn = fmaxf(m_r[r], mx[r]);
      alpha[r] = __expf(m_r[r] - mn);
      m_r[r] = mn;
    }
    float p[4][4];
#pragma unroll
    for (int c4 = 0; c4 < 4; ++c4)
#pragma unroll
      for (int r = 0; r < 4; ++r) {
        float pp = __expf(z[c4][r] - m_r[r]);
        p[c4][r] = pp;
        rs[r] += pp;
      }
#pragma unroll
    for (int d = 1; d < 16; d <<= 1)
#pragma unroll
      for (int r = 0; r < 4; ++r) rs[r] += __shfl_xor(rs[r], d);
#pragma unroll
    for (int r = 0; r < 4; ++r) l_r[r] = l_r[r] * alpha[r] + rs[r];
#pragma unroll
    for (int n = 0; n < 8; ++n)
#pragma unroll
      for (int r = 0; r < 4; ++r) o[n][r] *= alpha[r];

    // --- P (C-layout) -> per-wave LDS strip as hi/lo bf16 (trunc split) ---
#pragma unroll
    for (int c4 = 0; c4 < 4; ++c4)
#pragma unroll
      for (int r = 0; r < 4; ++r) {
        unsigned short h, lo;
        split1(p[c4][r], h, lo);
        int off = (quad * 4 + r) * 72 + c4 * 16 + l15;
        Ph[w][off] = h; Pl[w][off] = lo;
      }
    short8 pf[2], pg[2];
#pragma unroll
    for (int kq = 0; kq < 2; ++kq) {
      int off = l15 * 72 + kq * 32 + quad * 8;
      pf[kq] = *(const short8*)&Ph[w][off];
      pg[kq] = *(const short8*)&Pl[w][off];
    }

    // --- PV: O[16 x 128] += P @ V (P hi/lo x V single = 2-term) ---
#pragma unroll
    for (int n = 0; n < 8; ++n) {
      int drow = n * 16 + l15;
#pragma unroll
      for (int kq = 0; kq < 2; ++kq) {
        int off = drow * 64 + (((kq * 4 + quad) ^ (drow & 7)) * 8);
        short8 vhf = *(const short8*)&Vh[off];
        floatx4 c = o[n];
        c = __builtin_amdgcn_mfma_f32_16x16x32_bf16(pf[kq], vhf, c, 0, 0, 0);
        c = __builtin_amdgcn_mfma_f32_16x16x32_bf16(pg[kq], vhf, c, 0, 0, 0);
        o[n] = c;
      }
    }
  }

  // --- epilogue: write UNNORMALIZED partial + (m,l) ---
  const size_t grp = (size_t)(b * 32 + qt) * 3 + s3;
  float* Op = Opart + grp * 64 * 128;
#pragma unroll
  for (int n = 0; n < 8; ++n)
#pragma unroll
    for (int r = 0; r < 4; ++r)
      Op[(w * 16 + quad * 4 + r) * 128 + n * 16 + l15] = o[n][r];
  if (l15 == 0) {
#pragma unroll
    for (int r = 0; r < 4; ++r)
      ML[grp * 64 + w * 16 + quad * 4 + r] = make_float2(m_r[r], l_r[r]);
  }
}

// ---------------------------------------------------------------------------
// Kernel 3: merge the three split-KV partials.
// out = sum_i w_i O_i / sum_i w_i l_i,  w_i = exp(m_i - max m).
// Empty part: m=-1e30, l=0, O=0 -> w_i==0 (diagonal tile guarantees one
// non-empty part per row group).
// ---------------------------------------------------------------------------
__global__ __launch_bounds__(256) void merge_kernel(
    const float* __restrict__ Opart, const float2* __restrict__ ML,
    float* __restrict__ Out) {
  const int t = threadIdx.x;
  const int row = blockIdx.x * 2 + (t >> 7);   // 0..16383
  const int col = t & 127;
  const int grp = row >> 6;                    // b*32 + qt
  const int rin = row & 63;
  const size_t base = (size_t)grp * 3;
  float2 ml0 = ML[(base + 0) * 64 + rin];
  float2 ml1 = ML[(base + 1) * 64 + rin];
  float2 ml2 = ML[(base + 2) * 64 + rin];
  const float m = fmaxf(fmaxf(ml0.x, ml1.x), ml2.x);
  const float w0 = __expf(ml0.x - m), w1 = __expf(ml1.x - m), w2 = __expf(ml2.x - m);
  const float denom = w0 * ml0.y + w1 * ml1.y + w2 * ml2.y;
  const float o0 = Opart[((base + 0) * 64 + rin) * 128 + col];
  const float o1 = Opart[((base + 1) * 64 + rin) * 128 + col];
  const float o2 = Opart[((base + 2) * 64 + rin) * 128 + col];
  Out[(size_t)row * 128 + col] = (w0 * o0 + w1 * o1 + w2 * o2) / denom;
}

// ---------------------------------------------------------------------------
extern "C" void kernel_launch(void* const* d_in, const int* in_sizes, int n_in,
                              void* d_out, int out_size, void* d_ws, size_t ws_size,
                              hipStream_t stream) {
  const float* q  = (const float*)d_in[0];
  const float* k  = (const float*)d_in[1];
  const float* v  = (const float*)d_in[2];
  const float* Wq = (const float*)d_in[3];
  const float* bq = (const float*)d_in[4];
  const float* Wk = (const float*)d_in[5];
  const float* bk = (const float*)d_in[6];
  const float* Wv = (const float*)d_in[7];
  const float* bv = (const float*)d_in[8];
  float* out = (float*)d_out;

  unsigned short* Qb  = (unsigned short*)d_ws;                 // 4MB bf16 [s][d]
  unsigned short* Kb2 = Qb  + (size_t)MTOT * DQK;              // 4MB
  unsigned short* Vth = Kb2 + (size_t)MTOT * DQK;              // 4MB  [b][d][s]
  unsigned short* Whi = Vth + (size_t)MTOT * DQK;              // 768KB
  unsigned short* Wlo = Whi + (size_t)3 * DQK * DIN;           // 768KB
  float*  Opart = (float*)(Wlo + (size_t)3 * DQK * DIN);       // 24MB partials
  float2* ML    = (float2*)(Opart + (size_t)3 * MTOT * DQK);   // 384KB (m,l)

  GM g;
  compute_gtok(g.w);
  unsigned int t64 = 0;
  for (int t = 0; t < 32; ++t) if (g.w[t] != 0ULL) t64 |= (1u << t);

  hipLaunchKernelGGL(wconv_kernel, dim3(128, 3), dim3(256), 0, stream,
                     Wq, Wk, Wv, Whi, Wlo);
  hipLaunchKernelGGL(proj_kernel, dim3(256, 3), dim3(256), 0, stream,
                     q, k, v, Whi, Wlo, bq, bk, bv, Qb, Kb2, Vth);
  hipLaunchKernelGGL(attn_kernel, dim3(96, 8), dim3(256), 0, stream,
                     Qb, Kb2, Vth, Opart, ML, g, t64);
  hipLaunchKernelGGL(merge_kernel, dim3(MTOT / 2), dim3(256), 0, stream,
                     Opart, ML, out);
}

// Round 4
// 279.245 us; speedup vs baseline: 1.0361x; 1.0361x over previous
//
#include <hip/hip_runtime.h>
#include <cstdint>

constexpr int SEQ  = 2048;
constexpr int DIN  = 1024;
constexpr int DQK  = 128;
constexpr int NB   = 8;
constexpr int MTOT = NB * SEQ;   // 16384
constexpr float INV_SCALE = 0.08838834764831845f;  // 1/sqrt(128)

typedef __attribute__((ext_vector_type(8))) short  short8;
typedef __attribute__((ext_vector_type(4))) float  floatx4;
typedef __attribute__((ext_vector_type(4))) int    intx4;

struct GM { unsigned long long w[32]; };   // 2048-bit global-token mask

// ---------------------------------------------------------------------------
// Host-side reproduction of np.random.default_rng(0).choice(2048, 32, False).
// (verified correct since Round 1)
// ---------------------------------------------------------------------------
static void compute_gtok(unsigned long long bits[32]) {
  typedef unsigned __int128 u128;
  uint32_t pool[4];
  uint32_t hc = 0x43b0d7e5u;
  auto hashmix = [&hc](uint32_t v) -> uint32_t {
    v ^= hc; hc *= 0x931e8875u; v *= hc; v ^= v >> 16; return v;
  };
  auto mixf = [](uint32_t x, uint32_t y) -> uint32_t {
    uint32_t r = x * 0xca01f9ddu - y * 0x4973f715u;
    r ^= r >> 16; return r;
  };
  pool[0] = hashmix(0u);
  for (int i = 1; i < 4; ++i) pool[i] = hashmix(0u);
  for (int s = 0; s < 4; ++s)
    for (int d = 0; d < 4; ++d)
      if (s != d) pool[d] = mixf(pool[d], hashmix(pool[s]));
  uint32_t hb = 0x8b51f9ddu;
  uint32_t st[8];
  for (int i = 0; i < 8; ++i) {
    uint32_t dv = pool[i & 3];
    dv ^= hb; hb *= 0x58f38dedu; dv *= hb; dv ^= dv >> 16;
    st[i] = dv;
  }
  uint64_t sv[4];
  for (int i = 0; i < 4; ++i)
    sv[i] = (uint64_t)st[2 * i] | ((uint64_t)st[2 * i + 1] << 32);
  const u128 MUL = ((u128)2549297995355413924ULL << 64) | (u128)4865540595714422341ULL;
  u128 initstate = ((u128)sv[0] << 64) | sv[1];
  u128 initseq   = ((u128)sv[2] << 64) | sv[3];
  u128 state = 0;
  u128 inc = (initseq << 1) | 1;
  state = state * MUL + inc;
  state += initstate;
  state = state * MUL + inc;
  bool has32 = false; uint32_t cache32 = 0;
  auto next64 = [&]() -> uint64_t {
    state = state * MUL + inc;
    uint64_t hi = (uint64_t)(state >> 64);
    uint64_t lo = (uint64_t)state;
    unsigned rot = (unsigned)(state >> 122);
    uint64_t x = hi ^ lo;
    return (x >> rot) | (x << ((64u - rot) & 63u));
  };
  auto next32 = [&]() -> uint32_t {
    if (has32) { has32 = false; return cache32; }
    uint64_t n = next64();
    has32 = true; cache32 = (uint32_t)(n >> 32);
    return (uint32_t)n;
  };
  bool in_set[SEQ];
  for (int i = 0; i < SEQ; ++i) in_set[i] = false;
  for (uint32_t j = 2016; j < 2048; ++j) {
    uint32_t rng_excl = j + 1;
    uint64_t m = (uint64_t)next32() * rng_excl;
    uint32_t leftover = (uint32_t)m;
    if (leftover < rng_excl) {
      uint32_t threshold = (0xFFFFFFFFu - j) % rng_excl;
      while (leftover < threshold) {
        m = (uint64_t)next32() * rng_excl;
        leftover = (uint32_t)m;
      }
    }
    uint32_t val = (uint32_t)(m >> 32);
    if (in_set[val]) in_set[j] = true;
    else in_set[val] = true;
  }
  for (int i = 0; i < 32; ++i) bits[i] = 0ULL;
  for (int t = 0; t < SEQ; ++t)
    if (in_set[t]) bits[t >> 6] |= (1ULL << (t & 63));
}

// ---------------------------------------------------------------------------
// helpers
// ---------------------------------------------------------------------------
__device__ __forceinline__ void ldsld16(const void* g, void* l) {
  __builtin_amdgcn_global_load_lds(
      (const __attribute__((address_space(1))) unsigned int*)g,
      (__attribute__((address_space(3))) unsigned int*)l, 16, 0, 0);
}
__device__ __forceinline__ bool gbit(const GM& g, int j) {
  return (g.w[j >> 6] >> (j & 63)) & 1ULL;
}
// trunc-hi split: hi = RTZ bf16, lo = RTZ bf16 of residual (covered by 3-term)
__device__ __forceinline__ void split4(float4 x, unsigned hw[2], unsigned lw[2]) {
  unsigned u0 = __float_as_uint(x.x), u1 = __float_as_uint(x.y);
  unsigned u2 = __float_as_uint(x.z), u3 = __float_as_uint(x.w);
  hw[0] = __builtin_amdgcn_perm(u1, u0, 0x07060302u);
  hw[1] = __builtin_amdgcn_perm(u3, u2, 0x07060302u);
  unsigned r0 = __float_as_uint(x.x - __uint_as_float(u0 & 0xFFFF0000u));
  unsigned r1 = __float_as_uint(x.y - __uint_as_float(u1 & 0xFFFF0000u));
  unsigned r2 = __float_as_uint(x.z - __uint_as_float(u2 & 0xFFFF0000u));
  unsigned r3 = __float_as_uint(x.w - __uint_as_float(u3 & 0xFFFF0000u));
  lw[0] = __builtin_amdgcn_perm(r1, r0, 0x07060302u);
  lw[1] = __builtin_amdgcn_perm(r3, r2, 0x07060302u);
}
__device__ __forceinline__ void split1(float v, unsigned short& h, unsigned short& l) {
  unsigned u = __float_as_uint(v);
  h = (unsigned short)(u >> 16);
  float rr = v - __uint_as_float(u & 0xFFFF0000u);
  l = (unsigned short)(__float_as_uint(rr) >> 16);
}
__device__ __forceinline__ unsigned short bfr_rne(float v) {   // fp32->bf16 RNE
  unsigned u = __float_as_uint(v);
  return (unsigned short)((u + 0x7FFFu + ((u >> 16) & 1u)) >> 16);
}

// ---------------------------------------------------------------------------
// Kernel 0: convert W (3 x [128][1024] fp32) to hi/lo bf16 planes (flat).
// ---------------------------------------------------------------------------
__global__ __launch_bounds__(256) void wconv_kernel(
    const float* __restrict__ Wq, const float* __restrict__ Wk, const float* __restrict__ Wv,
    unsigned short* __restrict__ Whi, unsigned short* __restrict__ Wlo) {
  const float* W = blockIdx.y == 0 ? Wq : blockIdx.y == 1 ? Wk : Wv;
  size_t base = (size_t)blockIdx.y * DQK * DIN;
  int e = (blockIdx.x * 256 + threadIdx.x) * 4;
  float4 x = *(const float4*)&W[e];
  unsigned hw[2], lw[2];
  split4(x, hw, lw);
  *(uint2*)&Whi[base + e] = make_uint2(hw[0], hw[1]);
  *(uint2*)&Wlo[base + e] = make_uint2(lw[0], lw[1]);
}

// ---------------------------------------------------------------------------
// Kernel 1: projections via bf16 MFMA with hi/lo split (fp32-accurate).
// 64x128 block tile (grid 256x3 = 768 blocks = exactly 3/CU), 4 waves of
// 32x64 (2x4 of 16x16x32), K-chunk 64, 48KB LDS -> 3 blocks/CU resident.
// Round-3 pipeline (fixed R2 race): W via global_load_lds; X register-
// prefetched one chunk ahead. Counted vmcnt(4) is made VALID by pinning
// VMEM issue order with sched_barrier(0): [8 gload_lds W + convert/ds_write]
// SB0 [4 X prefetch] SB0 [vmcnt(4) lgkm(0) + s_barrier]. R2 NaN'd because
// the scheduler interleaved the X prefetch among the W gload_lds, breaking
// the count and letting waves cross the barrier before W arrived.
// which 0/1 -> Q/K bf16 [s][d]; which 2 -> Vt single RNE bf16 [b][d][s].
// ---------------------------------------------------------------------------
__global__ __launch_bounds__(256, 3) void proj_kernel(
    const float* __restrict__ xq, const float* __restrict__ xk, const float* __restrict__ xv,
    const unsigned short* __restrict__ Whi, const unsigned short* __restrict__ Wlo,
    const float* __restrict__ bq, const float* __restrict__ bk, const float* __restrict__ bv,
    unsigned short* __restrict__ Qb, unsigned short* __restrict__ Kb,
    unsigned short* __restrict__ Vth) {
  const int which = blockIdx.y;
  const float* X    = which == 0 ? xq : which == 1 ? xk : xv;
  const float* bias = which == 0 ? bq : which == 1 ? bk : bv;
  const int m0 = blockIdx.x * 64;

  __shared__ unsigned short Xh[64 * 64];    // 8KB
  __shared__ unsigned short Xl[64 * 64];    // 8KB
  __shared__ unsigned short Wh[128 * 64];   // 16KB (reused as VH in V epilogue)
  __shared__ unsigned short Wl[128 * 64];   // 16KB

  const int tid = threadIdx.x;
  const int w = tid >> 6, lane = tid & 63, l15 = lane & 15, quad = lane >> 4;
  const int mh = (w >> 1) * 32, nh = (w & 1) * 64;

  floatx4 acc[2][4] = {};
  float biasv[4];
#pragma unroll
  for (int j = 0; j < 4; ++j) biasv[j] = bias[nh + j * 16 + l15];

  const unsigned short* WhiP = Whi + (size_t)which * DQK * DIN;
  const unsigned short* WloP = Wlo + (size_t)which * DQK * DIN;

  // ---- X: per-thread loop-invariant addresses (4 float4 chunks) ----
  const float* xsrc[4];
  int xoff[4];
#pragma unroll
  for (int i = 0; i < 4; ++i) {
    int f = tid + i * 256;
    int r = f >> 4, c4 = f & 15;
    xsrc[i] = &X[(size_t)(m0 + r) * DIN + c4 * 4];     // + kb at load time
    xoff[i] = r * 64 + (((c4 >> 1) ^ (r & 7)) * 8) + (c4 & 1) * 4;
  }

  // ---- prologue: issue X prefetch for kb = 0 ----
  float4 xr[4];
#pragma unroll
  for (int i = 0; i < 4; ++i) xr[i] = *(const float4*)xsrc[i];

  for (int kb = 0; kb < DIN; kb += 64) {
    // top barrier: prior MFMA LDS reads done. NO vmcnt drain (X in flight).
    asm volatile("s_waitcnt lgkmcnt(0)" ::: "memory");
    __builtin_amdgcn_s_barrier();

    // --- region A: W gload_lds (8 ops) + X convert/ds_write ---
#pragma unroll
    for (int i = 0; i < 8; ++i) {
      int c = w * 8 + i;                 // 0..31: plane = c>>4, chunk cc = c&15
      int plane = c >> 4, cc = c & 15;
      int F = cc * 1024 + lane * 16;     // byte in 16KB plane tile
      int n = F >> 7, gs = (F >> 4) & 7, gl = gs ^ (n & 7);
      const unsigned short* gp = (plane ? WloP : WhiP) + (size_t)n * DIN + kb + gl * 8;
      ldsld16(gp, (char*)(plane ? Wl : Wh) + cc * 1024);
    }
#pragma unroll
    for (int i = 0; i < 4; ++i) {
      unsigned hw[2], lw[2];
      split4(xr[i], hw, lw);     // compiler auto-waits the 4 (oldest) X loads
      *(uint2*)&Xh[xoff[i]] = make_uint2(hw[0], hw[1]);
      *(uint2*)&Xl[xoff[i]] = make_uint2(lw[0], lw[1]);
    }
    // pin issue order: all of region A strictly before region B
    __builtin_amdgcn_sched_barrier(0);

    // --- region B: X prefetch for next chunk (dummy kb=0 on last iter so
    // the vmcnt(4) count below stays valid on every iteration) ---
    {
      int kb2 = (kb + 64 < DIN) ? kb + 64 : 0;
#pragma unroll
      for (int i = 0; i < 4; ++i) xr[i] = *(const float4*)(xsrc[i] + kb2);
    }
    __builtin_amdgcn_sched_barrier(0);

    // outstanding VMEM now exactly {8 W (oldest), 4 X (newest)}:
    // vmcnt(4) retires all W, leaves X prefetch in flight under MFMA.
    asm volatile("s_waitcnt vmcnt(4) lgkmcnt(0)" ::: "memory");
    __builtin_amdgcn_s_barrier();

    // --- MFMA: 2 k-steps of 32, hi/lo 3-term product ---
#pragma unroll
    for (int ks = 0; ks < 2; ++ks) {
      short8 Ah[2], Al[2], Bh[4], Bl[4];
#pragma unroll
      for (int ms = 0; ms < 2; ++ms) {
        int off = (mh + ms * 16 + l15) * 64 + (((ks * 4 + quad) ^ (l15 & 7)) * 8);
        Ah[ms] = *(const short8*)&Xh[off];
        Al[ms] = *(const short8*)&Xl[off];
      }
#pragma unroll
      for (int ns = 0; ns < 4; ++ns) {
        int off = (nh + ns * 16 + l15) * 64 + (((ks * 4 + quad) ^ (l15 & 7)) * 8);
        Bh[ns] = *(const short8*)&Wh[off];
        Bl[ns] = *(const short8*)&Wl[off];
      }
#pragma unroll
      for (int i = 0; i < 2; ++i)
#pragma unroll
        for (int j = 0; j < 4; ++j) {
          floatx4 c = acc[i][j];
          c = __builtin_amdgcn_mfma_f32_16x16x32_bf16(Ah[i], Bh[j], c, 0, 0, 0);
          c = __builtin_amdgcn_mfma_f32_16x16x32_bf16(Ah[i], Bl[j], c, 0, 0, 0);
          c = __builtin_amdgcn_mfma_f32_16x16x32_bf16(Al[i], Bh[j], c, 0, 0, 0);
          acc[i][j] = c;
        }
    }
  }

  // --- epilogue ---
  if (which < 2) {
    unsigned short* O = which == 0 ? Qb : Kb;
#pragma unroll
    for (int i = 0; i < 2; ++i)
#pragma unroll
      for (int j = 0; j < 4; ++j)
#pragma unroll
        for (int r = 0; r < 4; ++r) {
          int m = mh + i * 16 + quad * 4 + r;
          int n = nh + j * 16 + l15;
          O[(size_t)(m0 + m) * DQK + n] = bfr_rne(acc[i][j][r] + biasv[j]);
        }
  } else {
    // V: add bias, single RNE bf16, transpose to [d][s] via LDS (reuse Wh)
    __syncthreads();
    unsigned short* VH = Wh;   // 128(d) x 64(s) bf16, swizzled
#pragma unroll
    for (int i = 0; i < 2; ++i)
#pragma unroll
      for (int j = 0; j < 4; ++j)
#pragma unroll
        for (int r = 0; r < 4; ++r) {
          int s = mh + i * 16 + quad * 4 + r;
          int d = nh + j * 16 + l15;
          VH[d * 64 + (((s >> 3) ^ (d & 7)) * 8) + (s & 7)] =
              bfr_rne(acc[i][j][r] + biasv[j]);
        }
    __syncthreads();
    int b = m0 >> 11, s0 = m0 & 2047;
#pragma unroll
    for (int i = 0; i < 4; ++i) {
      int cch = i * 256 + tid;          // 1024 16B-chunks
      int d = cch >> 3, gI = cch & 7;
      int loff = d * 64 + ((gI ^ (d & 7)) * 8);
      intx4 vh = *(const intx4*)&VH[loff];
      *(intx4*)&Vth[((size_t)b * DQK + d) * SEQ + s0 + gI * 8] = vh;
    }
  }
}

// ---------------------------------------------------------------------------
// Kernel 2: flash attention, MFMA, 3-way split-KV (kt % 3 classes).
// grid.x = 96 (qt = x/3, s = x%3), grid.y = batch -> 768 blocks = 3/CU
// (50KB LDS, __launch_bounds__(256,3)). V single bf16 plane; P kept hi/lo
// (2-term PV). Writes UNNORMALIZED partial O + (m,l); merge3 combines.
// ---------------------------------------------------------------------------
__global__ __launch_bounds__(256, 3) void attn_kernel(
    const unsigned short* __restrict__ Qb, const unsigned short* __restrict__ Kb,
    const unsigned short* __restrict__ Vth,
    float* __restrict__ Opart, float2* __restrict__ ML, GM g, unsigned int t64) {
  __shared__ unsigned short Ks[64 * 128];   // swizzled, 16KB
  __shared__ unsigned short Vh[128 * 64];   // swizzled, 16KB
  __shared__ unsigned short Ph[4][16 * 72]; // per-wave P hi strips (stride 72)
  __shared__ unsigned short Pl[4][16 * 72]; // per-wave P lo strips

  const int tid = threadIdx.x;
  const int w = tid >> 6, lane = tid & 63, l15 = lane & 15, quad = lane >> 4;
  const int b = blockIdx.y;
  const int qt = blockIdx.x / 3, s3 = blockIdx.x - qt * 3;
  const int qs = qt * 64;

  // Q fragments (A-layout), held in registers for the whole block
  short8 qf[4];
  const unsigned short* Qrow = Qb + ((size_t)(b * SEQ + qs + w * 16 + l15)) * DQK;
#pragma unroll
  for (int j = 0; j < 4; ++j) qf[j] = *(const short8*)&Qrow[j * 32 + quad * 8];

  int rowi[4]; bool growb[4];
#pragma unroll
  for (int r = 0; r < 4; ++r) {
    rowi[r] = qs + w * 16 + quad * 4 + r;
    growb[r] = gbit(g, rowi[r]);
  }

  floatx4 o[8] = {};
  float m_r[4] = {-1e30f, -1e30f, -1e30f, -1e30f};
  float l_r[4] = {0.f, 0.f, 0.f, 0.f};

  const bool qhasg = (t64 >> qt) & 1;
  const unsigned short* KbB = Kb  + (size_t)b * SEQ * DQK;
  const unsigned short* VhB = Vth + (size_t)b * DQK * SEQ;

  for (int kt = s3; kt < 32; kt += 3) {    // 3-way split-KV
    const int ks0 = kt * 64;
    if (!((ks0 <= qs + 63) || ((t64 >> kt) & 1) || qhasg)) continue;   // block-uniform

    __syncthreads();   // prior tile's LDS reads complete
    // --- stage K / Vt (32 x 1KB chunks, swizzled gather) ---
#pragma unroll
    for (int i = 0; i < 8; ++i) {
      int c = w * 8 + i;
      if (c < 16) {
        int F = c * 1024 + lane * 16;
        int r = F >> 8, gs = (F >> 4) & 15, gl = gs ^ (r & 15);
        ldsld16(KbB + (size_t)(ks0 + r) * DQK + gl * 8, (char*)Ks + c * 1024);
      } else {
        int cc = c - 16;
        int F = cc * 1024 + lane * 16;
        int d = F >> 7, gs = (F >> 4) & 7, gl = gs ^ (d & 7);
        ldsld16(VhB + (size_t)d * SEQ + ks0 + gl * 8, (char*)Vh + cc * 1024);
      }
    }
    __syncthreads();   // staging visible

    // --- QK^T: S strip [16 q x 64 k] per wave ---
    floatx4 S[4];
#pragma unroll
    for (int c4 = 0; c4 < 4; ++c4) {
      floatx4 s = {0.f, 0.f, 0.f, 0.f};
#pragma unroll
      for (int j = 0; j < 4; ++j) {
        short8 kf = *(const short8*)&Ks[(c4 * 16 + l15) * 128 + (((j * 4 + quad) ^ l15) * 8)];
        s = __builtin_amdgcn_mfma_f32_16x16x32_bf16(qf[j], kf, s, 0, 0, 0);
      }
      S[c4] = s;
    }

    // --- mask + scale + online softmax ---
    float z[4][4];
    float mx[4] = {-1e30f, -1e30f, -1e30f, -1e30f};
#pragma unroll
    for (int c4 = 0; c4 < 4; ++c4) {
      int col = ks0 + c4 * 16 + l15;
      bool cg = gbit(g, col);
#pragma unroll
      for (int r = 0; r < 4; ++r) {
        bool ok = (col <= rowi[r]) || cg || growb[r];
        float zz = ok ? S[c4][r] * INV_SCALE : -1e30f;
        z[c4][r] = zz;
        mx[r] = fmaxf(mx[r], zz);
      }
    }
#pragma unroll
    for (int d = 1; d < 16; d <<= 1)
#pragma unroll
      for (int r = 0; r < 4; ++r) mx[r] = fmaxf(mx[r], __shfl_xor(mx[r], d));
    float alpha[4], rs[4] = {0.f, 0.f, 0.f, 0.f};
#pragma unroll
    for (int r = 0; r < 4; ++r) {
      float mn = fmaxf(m_r[r], mx[r]);
      alpha[r] = __expf(m_r[r] - mn);
      m_r[r] = mn;
    }
    float p[4][4];
#pragma unroll
    for (int c4 = 0; c4 < 4; ++c4)
#pragma unroll
      for (int r = 0; r < 4; ++r) {
        float pp = __expf(z[c4][r] - m_r[r]);
        p[c4][r] = pp;
        rs[r] += pp;
      }
#pragma unroll
    for (int d = 1; d < 16; d <<= 1)
#pragma unroll
      for (int r = 0; r < 4; ++r) rs[r] += __shfl_xor(rs[r], d);
#pragma unroll
    for (int r = 0; r < 4; ++r) l_r[r] = l_r[r] * alpha[r] + rs[r];
#pragma unroll
    for (int n = 0; n < 8; ++n)
#pragma unroll
      for (int r = 0; r < 4; ++r) o[n][r] *= alpha[r];

    // --- P (C-layout) -> per-wave LDS strip as hi/lo bf16 (trunc split) ---
#pragma unroll
    for (int c4 = 0; c4 < 4; ++c4)
#pragma unroll
      for (int r = 0; r < 4; ++r) {
        unsigned short h, lo;
        split1(p[c4][r], h, lo);
        int off = (quad * 4 + r) * 72 + c4 * 16 + l15;
        Ph[w][off] = h; Pl[w][off] = lo;
      }
    short8 pf[2], pg[2];
#pragma unroll
    for (int kq = 0; kq < 2; ++kq) {
      int off = l15 * 72 + kq * 32 + quad * 8;
      pf[kq] = *(const short8*)&Ph[w][off];
      pg[kq] = *(const short8*)&Pl[w][off];
    }

    // --- PV: O[16 x 128] += P @ V (P hi/lo x V single = 2-term) ---
#pragma unroll
    for (int n = 0; n < 8; ++n) {
      int drow = n * 16 + l15;
#pragma unroll
      for (int kq = 0; kq < 2; ++kq) {
        int off = drow * 64 + (((kq * 4 + quad) ^ (drow & 7)) * 8);
        short8 vhf = *(const short8*)&Vh[off];
        floatx4 c = o[n];
        c = __builtin_amdgcn_mfma_f32_16x16x32_bf16(pf[kq], vhf, c, 0, 0, 0);
        c = __builtin_amdgcn_mfma_f32_16x16x32_bf16(pg[kq], vhf, c, 0, 0, 0);
        o[n] = c;
      }
    }
  }

  // --- epilogue: write UNNORMALIZED partial + (m,l) ---
  const size_t grp = (size_t)(b * 32 + qt) * 3 + s3;
  float* Op = Opart + grp * 64 * 128;
#pragma unroll
  for (int n = 0; n < 8; ++n)
#pragma unroll
    for (int r = 0; r < 4; ++r)
      Op[(w * 16 + quad * 4 + r) * 128 + n * 16 + l15] = o[n][r];
  if (l15 == 0) {
#pragma unroll
    for (int r = 0; r < 4; ++r)
      ML[grp * 64 + w * 16 + quad * 4 + r] = make_float2(m_r[r], l_r[r]);
  }
}

// ---------------------------------------------------------------------------
// Kernel 3: merge the three split-KV partials.
// out = sum_i w_i O_i / sum_i w_i l_i,  w_i = exp(m_i - max m).
// Empty part: m=-1e30, l=0, O=0 -> w_i==0 (diagonal tile guarantees one
// non-empty part per row group).
// ---------------------------------------------------------------------------
__global__ __launch_bounds__(256) void merge_kernel(
    const float* __restrict__ Opart, const float2* __restrict__ ML,
    float* __restrict__ Out) {
  const int t = threadIdx.x;
  const int row = blockIdx.x * 2 + (t >> 7);   // 0..16383
  const int col = t & 127;
  const int grp = row >> 6;                    // b*32 + qt
  const int rin = row & 63;
  const size_t base = (size_t)grp * 3;
  float2 ml0 = ML[(base + 0) * 64 + rin];
  float2 ml1 = ML[(base + 1) * 64 + rin];
  float2 ml2 = ML[(base + 2) * 64 + rin];
  const float m = fmaxf(fmaxf(ml0.x, ml1.x), ml2.x);
  const float w0 = __expf(ml0.x - m), w1 = __expf(ml1.x - m), w2 = __expf(ml2.x - m);
  const float denom = w0 * ml0.y + w1 * ml1.y + w2 * ml2.y;
  const float o0 = Opart[((base + 0) * 64 + rin) * 128 + col];
  const float o1 = Opart[((base + 1) * 64 + rin) * 128 + col];
  const float o2 = Opart[((base + 2) * 64 + rin) * 128 + col];
  Out[(size_t)row * 128 + col] = (w0 * o0 + w1 * o1 + w2 * o2) / denom;
}

// ---------------------------------------------------------------------------
extern "C" void kernel_launch(void* const* d_in, const int* in_sizes, int n_in,
                              void* d_out, int out_size, void* d_ws, size_t ws_size,
                              hipStream_t stream) {
  const float* q  = (const float*)d_in[0];
  const float* k  = (const float*)d_in[1];
  const float* v  = (const float*)d_in[2];
  const float* Wq = (const float*)d_in[3];
  const float* bq = (const float*)d_in[4];
  const float* Wk = (const float*)d_in[5];
  const float* bk = (const float*)d_in[6];
  const float* Wv = (const float*)d_in[7];
  const float* bv = (const float*)d_in[8];
  float* out = (float*)d_out;

  unsigned short* Qb  = (unsigned short*)d_ws;                 // 4MB bf16 [s][d]
  unsigned short* Kb2 = Qb  + (size_t)MTOT * DQK;              // 4MB
  unsigned short* Vth = Kb2 + (size_t)MTOT * DQK;              // 4MB  [b][d][s]
  unsigned short* Whi = Vth + (size_t)MTOT * DQK;              // 768KB
  unsigned short* Wlo = Whi + (size_t)3 * DQK * DIN;           // 768KB
  float*  Opart = (float*)(Wlo + (size_t)3 * DQK * DIN);       // 24MB partials
  float2* ML    = (float2*)(Opart + (size_t)3 * MTOT * DQK);   // 384KB (m,l)

  GM g;
  compute_gtok(g.w);
  unsigned int t64 = 0;
  for (int t = 0; t < 32; ++t) if (g.w[t] != 0ULL) t64 |= (1u << t);

  hipLaunchKernelGGL(wconv_kernel, dim3(128, 3), dim3(256), 0, stream,
                     Wq, Wk, Wv, Whi, Wlo);
  hipLaunchKernelGGL(proj_kernel, dim3(256, 3), dim3(256), 0, stream,
                     q, k, v, Whi, Wlo, bq, bk, bv, Qb, Kb2, Vth);
  hipLaunchKernelGGL(attn_kernel, dim3(96, 8), dim3(256), 0, stream,
                     Qb, Kb2, Vth, Opart, ML, g, t64);
  hipLaunchKernelGGL(merge_kernel, dim3(MTOT / 2), dim3(256), 0, stream,
                     Opart, ML, out);
}